// Round 11
// baseline (947.868 us; speedup 1.0000x reference)
//
#include <hip/hip_runtime.h>
#include <hip/hip_bf16.h>

typedef __bf16 bf16x8 __attribute__((ext_vector_type(8)));
typedef float  f32x4  __attribute__((ext_vector_type(4)));

#define B_   16
#define CIN  64
#define COUT 64
#define H_   256
#define W_   256
#define TY   16
#define SLOT (258 * 64)

// ---------------- Kernel 1: modulate + demodulate weights -> bf16 [b][tap][co][ci]
__global__ void modw_kernel(const float* __restrict__ weight,
                            const float* __restrict__ y,
                            __bf16* __restrict__ w1g) {
  const int co = blockIdx.x * 4 + threadIdx.y;
  const int b  = blockIdx.y;
  const int ci = threadIdx.x;               // 64 threads = 1 wave
  const float c  = 0.041666666666666664f;   // (64*9)^-0.5 = 1/24
  const float yv = y[b*CIN + ci] * c;
  float w[9];
  float s = 0.0f;
#pragma unroll
  for (int t = 0; t < 9; ++t) {
    float wv = weight[(co*CIN + ci)*9 + t] * yv;
    w[t] = wv;
    s += wv * wv;
  }
#pragma unroll
  for (int off = 32; off > 0; off >>= 1) s += __shfl_xor(s, off, 64);
  const float d = rsqrtf(s + 1e-8f);
#pragma unroll
  for (int t = 0; t < 9; ++t)
    w1g[((b*9 + t)*COUT + co)*CIN + ci] = (__bf16)(w[t] * d);
}

// ---------------- staging helpers: one thread = 8 ci (group cg) x 4 px
__device__ __forceinline__ void stage_load(const float* __restrict__ X,
                                           int b, int yy, int tid, float4* f) {
  const int cg = tid >> 6;
  const int px_base = 4 * (tid & 63);
  const float* xrow = X + ((long)b * (CIN * H_ * W_) + (long)yy * W_);
#pragma unroll
  for (int j = 0; j < 8; ++j)
    f[j] = *reinterpret_cast<const float4*>(xrow + (long)(cg * 8 + j) * (H_ * W_) + px_base);
}

__device__ __forceinline__ void stage_write(__bf16* __restrict__ xs, int slot,
                                            int tid, const float4* f, bool valid) {
  const int cg = tid >> 6;
  const int px_base = 4 * (tid & 63);
  bf16x8 frag[4];
  if (valid) {
#pragma unroll
    for (int j = 0; j < 8; ++j) {
      frag[0][j] = (__bf16)f[j].x;
      frag[1][j] = (__bf16)f[j].y;
      frag[2][j] = (__bf16)f[j].z;
      frag[3][j] = (__bf16)f[j].w;
    }
  } else {
#pragma unroll
    for (int o = 0; o < 4; ++o)
#pragma unroll
      for (int j = 0; j < 8; ++j) frag[o][j] = (__bf16)0.f;
  }
#pragma unroll
  for (int oo = 0; oo < 4; ++oo) {
    const int o  = (oo + tid) & 3;            // rotate to spread write banks
    const int pl = px_base + o + 1;           // px_lds (cols 0 / 257 are zero pads)
    const int gs = cg ^ (pl & 7);             // XOR bank swizzle
    *reinterpret_cast<bf16x8*>(&xs[slot * SLOT + pl * 64 + gs * 8]) = frag[o];
  }
}

// ---------------- Kernel 2: strip-mined implicit-GEMM conv, SINGLE barrier/iter.
// One block per (b, 16-row strip). Rolling 4-slot LDS row buffer (132 KB).
// With 4 slots, the written slot (y+2)&3 is disjoint from all read slots
// ((y-1,y,y+1)&3), so the post-compute barrier of the 3-ring is unnecessary:
// RAW (row y+2 read at iter y+1) and WAR (slot last read at iter y-1) are both
// ordered by the single top-of-iter barrier. Barrier drains per iter: 2 -> 1.
__global__ __launch_bounds__(512, 2)
void conv_kernel(const float* __restrict__ X,
                 const __bf16* __restrict__ w1g,
                 float* __restrict__ out) {
  const int y0   = blockIdx.x * TY;
  const int b    = blockIdx.y;
  const int tid  = threadIdx.x;
  const int lane = tid & 63;
  const int wv   = tid >> 6;        // wave 0..7
  const int cgw  = wv & 1;          // co half (32 co)
  const int pg   = wv >> 1;         // px quarter (64 px)
  const int q    = lane >> 4;       // 0..3
  const int n    = lane & 15;       // 0..15

  __shared__ __bf16 xs[4 * SLOT];   // 132 KB: 4 row slots [258][64] bf16, swizzled

  // zero the pad columns (px_lds = 0 and 257) of all 4 slots, once
  {
    const int s = tid >> 7, r = tid & 127;    // 4 slots x 128 threads
    const int col = (r < 64) ? 0 : 257;
    xs[s * SLOT + col * 64 + (r & 63)] = (__bf16)0.f;
  }

  // hoisted weight fragments: B-operand, col = co = n, k = ci = q*8+j (+32 for ks=1)
  bf16x8 wfr[2][9][2];
#pragma unroll
  for (int c2 = 0; c2 < 2; ++c2) {
    const int co = cgw * 32 + c2 * 16 + n;
#pragma unroll
    for (int tap = 0; tap < 9; ++tap) {
      const __bf16* wp = w1g + ((b * 9 + tap) * COUT + co) * CIN + q * 8;
      wfr[c2][tap][0] = *reinterpret_cast<const bf16x8*>(wp);        // ci = q*8+j
      wfr[c2][tap][1] = *reinterpret_cast<const bf16x8*>(wp + 32);   // ci = 32+q*8+j
    }
  }

  // prologue: stage rows y0-1, y0, y0+1 into slot (row+4)&3
  {
    float4 f[8];
#pragma unroll
    for (int k = 0; k < 3; ++k) {
      const int yy = y0 - 1 + k;
      const bool valid = (yy >= 0);             // yy <= y0+1 <= 241 < H_
      if (valid) stage_load(X, b, yy, tid, f);
      stage_write(xs, (yy + 4) & 3, tid, f, valid);
    }
  }

  float4 pf[8];                     // prefetch registers for row y+2
  for (int ty = 0; ty < TY; ++ty) {
    const int y = y0 + ty;
    __syncthreads();                // the ONLY barrier: staged rows visible,
                                    // prior iter's reads of slot (y+2)&3 done

    const int yy = y + 2;
    const bool do_pf = (ty < TY - 1);              // row y0+16 staged at ty=14
    const bool pf_ok = do_pf && (yy < H_);
    if (pf_ok) stage_load(X, b, yy, tid, pf);      // issue loads; land during MFMA

    f32x4 acc[2][4];
#pragma unroll
    for (int c2 = 0; c2 < 2; ++c2)
#pragma unroll
      for (int nt = 0; nt < 4; ++nt) acc[c2][nt] = (f32x4){0.f, 0.f, 0.f, 0.f};

#pragma unroll
    for (int dy = 0; dy < 3; ++dy) {
      const __bf16* sl = &xs[((y + dy + 3) & 3) * SLOT];   // row y-1+dy
#pragma unroll
      for (int dx = 0; dx < 3; ++dx) {
        const int tap = dy * 3 + dx;
        const int p3 = (n + dx) & 7;               // px&7 (pg*64, nt*16 = 0 mod 8)
        const int o0 = (q ^ p3) * 8;
        const int o1 = ((q + 4) ^ p3) * 8;
#pragma unroll
        for (int nt = 0; nt < 4; ++nt) {
          const int px = pg * 64 + nt * 16 + n + dx;
          const bf16x8 a0 = *reinterpret_cast<const bf16x8*>(&sl[px * 64 + o0]);
          const bf16x8 a1 = *reinterpret_cast<const bf16x8*>(&sl[px * 64 + o1]);
          acc[0][nt] = __builtin_amdgcn_mfma_f32_16x16x32_bf16(a0, wfr[0][tap][0], acc[0][nt], 0, 0, 0);
          acc[0][nt] = __builtin_amdgcn_mfma_f32_16x16x32_bf16(a1, wfr[0][tap][1], acc[0][nt], 0, 0, 0);
          acc[1][nt] = __builtin_amdgcn_mfma_f32_16x16x32_bf16(a0, wfr[1][tap][0], acc[1][nt], 0, 0, 0);
          acc[1][nt] = __builtin_amdgcn_mfma_f32_16x16x32_bf16(a1, wfr[1][tap][1], acc[1][nt], 0, 0, 0);
        }
      }
    }
    // NO second barrier: write slot (y+2)&3 is disjoint from all read slots

    // epilogue: D[row=px][col=co]: lane (q,n) holds 4 consecutive px at co-offset n
#pragma unroll
    for (int c2 = 0; c2 < 2; ++c2) {
      const int co = cgw * 32 + c2 * 16 + n;
#pragma unroll
      for (int nt = 0; nt < 4; ++nt) {
        const int px0 = pg * 64 + nt * 16 + q * 4;
        *reinterpret_cast<float4*>(out + ((long)(b * COUT + co) * H_ + y) * W_ + px0) =
            *reinterpret_cast<const float4*>(&acc[c2][nt]);
      }
    }

    // write prefetched row y+2 into slot (y+2)&3; visible after next barrier
    if (do_pf) stage_write(xs, (yy + 4) & 3, tid, pf, pf_ok);
  }
}

extern "C" void kernel_launch(void* const* d_in, const int* in_sizes, int n_in,
                              void* d_out, int out_size, void* d_ws, size_t ws_size,
                              hipStream_t stream) {
  const float* X = (const float*)d_in[0];   // (16, 64, 256, 256) fp32
  const float* y = (const float*)d_in[1];   // (16, 64) fp32
  const float* w = (const float*)d_in[2];   // (64, 64, 3, 3) fp32
  float* outp = (float*)d_out;              // (16, 64, 256, 256) fp32
  __bf16* w1g = (__bf16*)d_ws;              // 16*9*64*64 bf16 = 1.13 MB scratch

  modw_kernel<<<dim3(COUT / 4, B_), dim3(64, 4), 0, stream>>>(w, y, w1g);
  conv_kernel<<<dim3(H_ / TY, B_), 512, 0, stream>>>(X, w1g, outp);
}

// Round 12
// 772.201 us; speedup vs baseline: 1.2275x; 1.2275x over previous
//
#include <hip/hip_runtime.h>
#include <hip/hip_bf16.h>

typedef __bf16 bf16x8 __attribute__((ext_vector_type(8)));
typedef float  f32x4  __attribute__((ext_vector_type(4)));

#define B_   16
#define CIN  64
#define COUT 64
#define H_   256
#define W_   256
#define TY   16
#define SLOT (258 * 64)

// ---------------- Kernel 1: modulate + demodulate weights -> bf16 [b][tap][co][ci]
__global__ void modw_kernel(const float* __restrict__ weight,
                            const float* __restrict__ y,
                            __bf16* __restrict__ w1g) {
  const int co = blockIdx.x * 4 + threadIdx.y;
  const int b  = blockIdx.y;
  const int ci = threadIdx.x;               // 64 threads = 1 wave
  const float c  = 0.041666666666666664f;   // (64*9)^-0.5 = 1/24
  const float yv = y[b*CIN + ci] * c;
  float w[9];
  float s = 0.0f;
#pragma unroll
  for (int t = 0; t < 9; ++t) {
    float wv = weight[(co*CIN + ci)*9 + t] * yv;
    w[t] = wv;
    s += wv * wv;
  }
#pragma unroll
  for (int off = 32; off > 0; off >>= 1) s += __shfl_xor(s, off, 64);
  const float d = rsqrtf(s + 1e-8f);
#pragma unroll
  for (int t = 0; t < 9; ++t)
    w1g[((b*9 + t)*COUT + co)*CIN + ci] = (__bf16)(w[t] * d);
}

// ---------------- staging helpers (1024 threads): one thread = 8 ci x 2 px
__device__ __forceinline__ void stage_load(const float* __restrict__ X,
                                           int b, int yy, int tid, float2* f) {
  const int cg = tid >> 7;                  // ci group 0..7
  const int px_base = 2 * (tid & 127);      // 2 px per thread, 256 px total
  const float* xrow = X + ((long)b * (CIN * H_ * W_) + (long)yy * W_);
#pragma unroll
  for (int j = 0; j < 8; ++j)
    f[j] = *reinterpret_cast<const float2*>(xrow + (long)(cg * 8 + j) * (H_ * W_) + px_base);
}

__device__ __forceinline__ void stage_write(__bf16* __restrict__ xs, int slot,
                                            int tid, const float2* f, bool valid) {
  const int cg = tid >> 7;
  const int px_base = 2 * (tid & 127);
  bf16x8 frag[2];
  if (valid) {
#pragma unroll
    for (int j = 0; j < 8; ++j) {
      frag[0][j] = (__bf16)f[j].x;
      frag[1][j] = (__bf16)f[j].y;
    }
  } else {
#pragma unroll
    for (int o = 0; o < 2; ++o)
#pragma unroll
      for (int j = 0; j < 8; ++j) frag[o][j] = (__bf16)0.f;
  }
#pragma unroll
  for (int oo = 0; oo < 2; ++oo) {
    const int o  = (oo + tid) & 1;            // rotate to spread write banks
    const int pl = px_base + o + 1;           // px_lds (cols 0 / 257 are zero pads)
    const int gs = cg ^ (pl & 7);             // XOR bank swizzle
    *reinterpret_cast<bf16x8*>(&xs[slot * SLOT + pl * 64 + gs * 8]) = frag[o];
  }
}

// ---------------- Kernel 2: strip-mined implicit-GEMM conv, 16 waves/block.
// One block per (b, 16-row strip), 1024 threads = 16 waves = 4 waves/SIMD.
// Same proven 3-slot ring + 2-barrier schedule as the 314us kernel; the ONLY
// change is wave count: 4-deep wave TLP per SIMD hides the ds_read->MFMA and
// weight-load->MFMA latency chains that dominated at 2 waves/SIMD.
// 16 waves = 2 co-halves x 8 px-groups(32 px); per wave 2 co-tiles x 2 px-tiles.
__global__ __launch_bounds__(1024, 4)
void conv_kernel(const float* __restrict__ X,
                 const __bf16* __restrict__ w1g,
                 float* __restrict__ out) {
  const int y0   = blockIdx.x * TY;
  const int b    = blockIdx.y;
  const int tid  = threadIdx.x;
  const int lane = tid & 63;
  const int wv   = tid >> 6;        // wave 0..15
  const int cgw  = wv & 1;          // co half (32 co)
  const int pg   = wv >> 1;         // px group 0..7 (32 px each)
  const int q    = lane >> 4;       // 0..3
  const int n    = lane & 15;       // 0..15

  __shared__ __bf16 xs[3 * SLOT];   // 99 KB: 3 row slots [258][64] bf16, swizzled

  // zero the pad columns (px_lds = 0 and 257) of all 3 slots, once
  if (tid < 384) {
    const int s = tid >> 7, r = tid & 127;
    const int col = (r < 64) ? 0 : 257;
    xs[s * SLOT + col * 64 + (r & 63)] = (__bf16)0.f;
  }

  // hoisted weight fragments: B-operand, col = co = n, k = ci = q*8+j (+32 for ks=1)
  bf16x8 wfr[2][9][2];
#pragma unroll
  for (int c2 = 0; c2 < 2; ++c2) {
    const int co = cgw * 32 + c2 * 16 + n;
#pragma unroll
    for (int tap = 0; tap < 9; ++tap) {
      const __bf16* wp = w1g + ((b * 9 + tap) * COUT + co) * CIN + q * 8;
      wfr[c2][tap][0] = *reinterpret_cast<const bf16x8*>(wp);        // ci = q*8+j
      wfr[c2][tap][1] = *reinterpret_cast<const bf16x8*>(wp + 32);   // ci = 32+q*8+j
    }
  }

  // prologue: stage rows y0-1, y0, y0+1 into slot (row+3)%3
  {
    float2 f[8];
#pragma unroll
    for (int k = 0; k < 3; ++k) {
      const int yy = y0 - 1 + k;
      const bool valid = (yy >= 0);             // yy <= y0+1 <= 241 < H_
      if (valid) stage_load(X, b, yy, tid, f);
      stage_write(xs, (yy + 3) % 3, tid, f, valid);
    }
  }

  float2 pf[8];                     // prefetch registers for row y+2 (16 VGPR)
  for (int ty = 0; ty < TY; ++ty) {
    const int y = y0 + ty;
    __syncthreads();                               // S1: staged rows visible

    const int yy = y + 2;
    const bool do_pf = (ty < TY - 1);
    const bool pf_ok = do_pf && (yy < H_);
    if (pf_ok) stage_load(X, b, yy, tid, pf);      // issue loads; land during MFMA

    f32x4 acc[2][2];
#pragma unroll
    for (int c2 = 0; c2 < 2; ++c2)
#pragma unroll
      for (int nt = 0; nt < 2; ++nt) acc[c2][nt] = (f32x4){0.f, 0.f, 0.f, 0.f};

#pragma unroll
    for (int dy = 0; dy < 3; ++dy) {
      const __bf16* sl = &xs[((y - 1 + dy + 3) % 3) * SLOT];   // row y-1+dy
#pragma unroll
      for (int dx = 0; dx < 3; ++dx) {
        const int tap = dy * 3 + dx;
        const int p3 = (n + dx) & 7;               // px&7 (pg*32, nt*16 = 0 mod 8)
        const int o0 = (q ^ p3) * 8;
        const int o1 = ((q + 4) ^ p3) * 8;
#pragma unroll
        for (int nt = 0; nt < 2; ++nt) {
          const int px = pg * 32 + nt * 16 + n + dx;
          const bf16x8 a0 = *reinterpret_cast<const bf16x8*>(&sl[px * 64 + o0]);
          const bf16x8 a1 = *reinterpret_cast<const bf16x8*>(&sl[px * 64 + o1]);
          acc[0][nt] = __builtin_amdgcn_mfma_f32_16x16x32_bf16(a0, wfr[0][tap][0], acc[0][nt], 0, 0, 0);
          acc[0][nt] = __builtin_amdgcn_mfma_f32_16x16x32_bf16(a1, wfr[0][tap][1], acc[0][nt], 0, 0, 0);
          acc[1][nt] = __builtin_amdgcn_mfma_f32_16x16x32_bf16(a0, wfr[1][tap][0], acc[1][nt], 0, 0, 0);
          acc[1][nt] = __builtin_amdgcn_mfma_f32_16x16x32_bf16(a1, wfr[1][tap][1], acc[1][nt], 0, 0, 0);
        }
      }
    }
    __syncthreads();                               // S2: frees slot (y-1)%3; pins
                                                   // stage_write after compute

    // epilogue: D[row=px][col=co]: lane (q,n) holds 4 consecutive px at co-offset n
#pragma unroll
    for (int c2 = 0; c2 < 2; ++c2) {
      const int co = cgw * 32 + c2 * 16 + n;
#pragma unroll
      for (int nt = 0; nt < 2; ++nt) {
        const int px0 = pg * 32 + nt * 16 + q * 4;
        *reinterpret_cast<float4*>(out + ((long)(b * COUT + co) * H_ + y) * W_ + px0) =
            *reinterpret_cast<const float4*>(&acc[c2][nt]);
      }
    }

    // write prefetched row y+2 into slot freed by S2; visible after next S1
    if (do_pf) stage_write(xs, yy % 3, tid, pf, pf_ok);
  }
}

extern "C" void kernel_launch(void* const* d_in, const int* in_sizes, int n_in,
                              void* d_out, int out_size, void* d_ws, size_t ws_size,
                              hipStream_t stream) {
  const float* X = (const float*)d_in[0];   // (16, 64, 256, 256) fp32
  const float* y = (const float*)d_in[1];   // (16, 64) fp32
  const float* w = (const float*)d_in[2];   // (64, 64, 3, 3) fp32
  float* outp = (float*)d_out;              // (16, 64, 256, 256) fp32
  __bf16* w1g = (__bf16*)d_ws;              // 16*9*64*64 bf16 = 1.13 MB scratch

  modw_kernel<<<dim3(COUT / 4, B_), dim3(64, 4), 0, stream>>>(w, y, w1g);
  conv_kernel<<<dim3(H_ / TY, B_), 1024, 0, stream>>>(X, w1g, outp);
}